// Round 2
// baseline (210.400 us; speedup 1.0000x reference)
//
#include <hip/hip_runtime.h>

// Problem constants: h[B,G,D], W[G,D,K], out[B,G,K]
#define Gn   100
#define Bn   256
#define Dn   768
#define Kn   128
#define LDP  40   // LDS leading dim in shorts (32+8): 2-way max bank aliasing (free)

typedef __attribute__((ext_vector_type(8))) short short8;
typedef __attribute__((ext_vector_type(4))) float f32x4;

// pack two fp32 -> two bf16 (round-to-nearest, ties away) in 3 VALU
__device__ inline unsigned pack2(float lo, float hi) {
  union { float f; unsigned u; } a, b; a.f = lo; b.f = hi;
  return __builtin_amdgcn_perm(b.u + 0x8000u, a.u + 0x8000u, 0x07060302u);
}

// Non-draining block barrier: execution sync + LDS-write visibility ONLY.
// All global loads here target registers (per-wave private), so skipping the
// vmcnt drain is safe; lgkmcnt(0) makes LDS stores visible.
__device__ inline void barrier_nodrain() {
  asm volatile("s_waitcnt lgkmcnt(0)\n\ts_barrier" ::: "memory");
}

// Fused grouped GEMM, 64x64 tile, 4 waves (2x2), mfma_f32_16x16x32_bf16.
// R2: (a) B global loads contiguous dwordx2 (col-pair x 4 d-rows per thread):
//     6 VMEM/thread-step (was 10), in-register repack to the PROVEN [n][k]
//     LDS layout (read path identical to the passing R0 kernel).
//     (b) depth-3 register prefetch: loads issued at iter c are consumed at
//     iter c+2 -> TWO barriers of latency cover (was one). Triple LDS
//     buffering already supports this schedule.
__global__ __launch_bounds__(256, 3) void groupfc_kernel(
    const float* __restrict__ h, const float* __restrict__ W,
    float* __restrict__ out) {
  // grid 832 = 104*8; decode: xcd=id%8 -> g%8, tile = (id>>3)%8
  const int id   = blockIdx.x;
  const int xcd  = id & 7;
  const int rest = id >> 3;
  const int tl   = rest & 7;
  const int g    = (rest >> 3) * 8 + xcd;
  if (g >= Gn) return;                       // pad blocks exit before any barrier
  const int mt   = tl >> 1;                  // 0..3 (rows of 64)
  const int nt   = tl & 1;                   // 0..1 (cols of 64)

  const int t    = threadIdx.x;
  const int lane = t & 63;
  const int wave = t >> 6;
  const int wm   = wave >> 1, wn = wave & 1; // 2x2 wave grid, 32x32 each
  const int l15  = lane & 15, quad = lane >> 4;

  __shared__ __align__(16) short Af[3][64 * LDP];  // [m][k] bf16, 3 buffers
  __shared__ __align__(16) short Bf[3][64 * LDP];  // [n][k] bf16, 3 buffers
  __shared__ float AssqL[64];
  __shared__ float BssqL[4][64];

  f32x4 acc00 = {0.f,0.f,0.f,0.f};
  f32x4 acc01 = acc00, acc10 = acc00, acc11 = acc00;

  // A staging: thread -> (row ar, 8 contiguous k at ac); two dwordx4 per chunk
  const int ar = t >> 2;
  const int ac = (t & 3) * 8;
  const float* aptr = h + ((size_t)(mt * 64 + ar) * Gn + g) * Dn + ac;

  // B staging: thread -> (col pair c2..c2+1, 4 d-rows at bq*4); dwordx2 loads,
  // each instruction = two 256B coalesced segments per wave.
  const int c2 = (t & 31) * 2;               // 0,2,..,62
  const int bq = t >> 5;                     // 0..7
  const float* bptr = W + (size_t)g * (Dn * Kn) + (size_t)(bq * 4) * Kn + nt * 64 + c2;

  const int koff = quad * 8;                 // A/B fragment: k = quad*8 + j
  const int m0   = wm * 32 + l15;
  const int n0   = wn * 32 + l15;

  float assq = 0.f, bs0 = 0.f, bs1 = 0.f;
  float4 Ar_[3][2];                          // 3 register sets (depth-3 prefetch)
  float2 Br_[3][4];

  auto load_set = [&](int c, int s) {        // issue chunk-c loads into set s
    const int d0 = c * 32;
    Ar_[s][0] = *(const float4*)(aptr + d0);
    Ar_[s][1] = *(const float4*)(aptr + d0 + 4);
    const float* bp = bptr + (size_t)d0 * Kn;
#pragma unroll
    for (int i = 0; i < 4; ++i) Br_[s][i] = *(const float2*)(bp + (size_t)i * Kn);
  };

  auto pack_set = [&](int c, int s) {        // fp32 ssq + bf16 pack -> buf[c%3]
    const float4 a0 = Ar_[s][0], a1 = Ar_[s][1];
    assq += a0.x*a0.x + a0.y*a0.y + a0.z*a0.z + a0.w*a0.w
          + a1.x*a1.x + a1.y*a1.y + a1.z*a1.z + a1.w*a1.w;
    uint4 ap;
    ap.x = pack2(a0.x, a0.y); ap.y = pack2(a0.z, a0.w);
    ap.z = pack2(a1.x, a1.y); ap.w = pack2(a1.z, a1.w);
    *(uint4*)&Af[c % 3][ar * LDP + ac] = ap;

    const float2 b0 = Br_[s][0], b1 = Br_[s][1], b2 = Br_[s][2], b3 = Br_[s][3];
    bs0 += b0.x*b0.x + b1.x*b1.x + b2.x*b2.x + b3.x*b3.x;
    bs1 += b0.y*b0.y + b1.y*b1.y + b2.y*b2.y + b3.y*b3.y;
    // col c2:   k-run bq*4..bq*4+3 ; col c2+1: same k-run, next row
    uint2 w0, w1;
    w0.x = pack2(b0.x, b1.x); w0.y = pack2(b2.x, b3.x);
    w1.x = pack2(b0.y, b1.y); w1.y = pack2(b2.y, b3.y);
    *(uint2*)&Bf[c % 3][c2 * LDP + bq * 4]       = w0;
    *(uint2*)&Bf[c % 3][(c2 + 1) * LDP + bq * 4] = w1;
  };

  // ---- prologue: chunks 0,1,2 in flight; pack 0 ----
  load_set(0, 0);
  load_set(1, 1);
  load_set(2, 2);
  pack_set(0, 0);

  // ---- main loop: 24 K-steps, ONE non-draining barrier each ----
  // Window [bar(c), bar(c+1)] reads buf[c%3], writes buf[(c+1)%3]: disjoint;
  // buf[c%3] is next rewritten by pack(c+3) at iter c+2, after barrier c+1
  // has retired all iter-c reads.
#pragma unroll
  for (int c = 0; c < 24; ++c) {
    if (c + 3 < 24) load_set(c + 3, (c + 3) % 3);   // 2-barrier-deep cover
    if (c + 1 < 24) pack_set(c + 1, (c + 1) % 3);
    barrier_nodrain();

    const int b = c % 3;
    short8 af0 = *(const short8*)&Af[b][m0 * LDP + koff];
    short8 af1 = *(const short8*)&Af[b][(m0 + 16) * LDP + koff];
    short8 bf0 = *(const short8*)&Bf[b][n0 * LDP + koff];
    short8 bf1 = *(const short8*)&Bf[b][(n0 + 16) * LDP + koff];

    acc00 = __builtin_amdgcn_mfma_f32_16x16x32_bf16(af0, bf0, acc00, 0, 0, 0);
    acc01 = __builtin_amdgcn_mfma_f32_16x16x32_bf16(af0, bf1, acc01, 0, 0, 0);
    acc10 = __builtin_amdgcn_mfma_f32_16x16x32_bf16(af1, bf0, acc10, 0, 0, 0);
    acc11 = __builtin_amdgcn_mfma_f32_16x16x32_bf16(af1, bf1, acc11, 0, 0, 0);
  }

  // ---- block-reduce the norms ----
  assq += __shfl_xor(assq, 1);               // 4 threads (t&3) share row ar
  assq += __shfl_xor(assq, 2);
  if ((t & 3) == 0) AssqL[ar] = assq;
  // per-col B ssq: threads sharing a col differ in lane bit 5 (in-wave) and wave
  bs0 += __shfl_xor(bs0, 32);
  bs1 += __shfl_xor(bs1, 32);
  if (lane < 32) {                           // cols lane*2, lane*2+1
    BssqL[wave][lane * 2]     = bs0;
    BssqL[wave][lane * 2 + 1] = bs1;
  }
  __syncthreads();                           // one draining barrier: loop is done

  // ---- epilogue: scale by 1/max(||h_row||,eps) * 1/max(||w_col||,eps) ----
  // C/D layout: col = lane&15, row = quad*4 + reg
  const float ws0 = BssqL[0][n0] + BssqL[1][n0] + BssqL[2][n0] + BssqL[3][n0];
  const float ws1 = BssqL[0][n0+16] + BssqL[1][n0+16] + BssqL[2][n0+16] + BssqL[3][n0+16];
  const float wi0 = 1.0f / fmaxf(sqrtf(ws0), 1e-12f);
  const float wi1 = 1.0f / fmaxf(sqrtf(ws1), 1e-12f);

#pragma unroll
  for (int mi = 0; mi < 2; ++mi) {
#pragma unroll
    for (int r = 0; r < 4; ++r) {
      const int lr = wm * 32 + mi * 16 + quad * 4 + r;   // local row in tile
      const float hs = 1.0f / fmaxf(sqrtf(AssqL[lr]), 1e-12f);
      const float v0 = (mi ? acc10[r] : acc00[r]) * hs * wi0;
      const float v1 = (mi ? acc11[r] : acc01[r]) * hs * wi1;
      const int row = mt * 64 + lr;
      const size_t ob = ((size_t)row * Gn + g) * Kn + nt * 64;
      out[ob + wn * 32 + l15]      = v0;
      out[ob + wn * 32 + l15 + 16] = v1;
    }
  }
}

extern "C" void kernel_launch(void* const* d_in, const int* in_sizes, int n_in,
                              void* d_out, int out_size, void* d_ws, size_t ws_size,
                              hipStream_t stream) {
  const float* h = (const float*)d_in[0];          // [B,G,D]
  const float* W = (const float*)d_in[1];          // [G,D,K]
  float* out = (float*)d_out;                      // [B,G,K]
  hipLaunchKernelGGL(groupfc_kernel, dim3(832), dim3(256), 0, stream, h, W, out);
}

// Round 3
// 173.863 us; speedup vs baseline: 1.2101x; 1.2101x over previous
//
#include <hip/hip_runtime.h>

// Problem constants: h[B,G,D], W[G,D,K], out[B,G,K]
#define Gn   100
#define Bn   256
#define Dn   768
#define Kn   128
#define LDP  40   // LDS leading dim in shorts (32+8): 2-way max bank aliasing (free)

typedef __attribute__((ext_vector_type(8))) short short8;
typedef __attribute__((ext_vector_type(4))) float f32x4;

// pack two fp32 -> two bf16 (round-to-nearest, ties away) in 3 VALU
__device__ inline unsigned pack2(float lo, float hi) {
  union { float f; unsigned u; } a, b; a.f = lo; b.f = hi;
  return __builtin_amdgcn_perm(b.u + 0x8000u, a.u + 0x8000u, 0x07060302u);
}

// Non-draining block barrier: execution sync + LDS-write visibility ONLY.
// All global loads here target registers (per-wave private), so skipping the
// vmcnt drain is safe; lgkmcnt(0) makes LDS stores visible.
__device__ inline void barrier_nodrain() {
  asm volatile("s_waitcnt lgkmcnt(0)\n\ts_barrier" ::: "memory");
}

// Fused grouped GEMM, 64x64 tile, 4 waves (2x2), mfma_f32_16x16x32_bf16.
// R3: depth-3 register prefetch done RIGHT: manual 3-phase unroll with NAMED
// register sets (A0/A1/A2, B0/B1/B2) and literal LDS buffer indices -- no
// runtime-indexed register arrays (R2 put them in scratch: WRITE_SIZE 12.8
// -> 82.4 MB, the whole regression). Loads issued at iter c are consumed at
// iter c+2: TWO barriers of latency cover. B loads contiguous dwordx2.
struct ASet { float4 a0, a1; };
struct BSet { float2 b0, b1, b2, b3; };

__global__ __launch_bounds__(256, 3) void groupfc_kernel(
    const float* __restrict__ h, const float* __restrict__ W,
    float* __restrict__ out) {
  // grid 832 = 104*8; decode: xcd=id%8 -> g%8, tile = (id>>3)%8
  const int id   = blockIdx.x;
  const int xcd  = id & 7;
  const int rest = id >> 3;
  const int tl   = rest & 7;
  const int g    = (rest >> 3) * 8 + xcd;
  if (g >= Gn) return;                       // pad blocks exit before any barrier
  const int mt   = tl >> 1;                  // 0..3 (rows of 64)
  const int nt   = tl & 1;                   // 0..1 (cols of 64)

  const int t    = threadIdx.x;
  const int lane = t & 63;
  const int wave = t >> 6;
  const int wm   = wave >> 1, wn = wave & 1; // 2x2 wave grid, 32x32 each
  const int l15  = lane & 15, quad = lane >> 4;

  __shared__ __align__(16) short Af[3][64 * LDP];  // [m][k] bf16, 3 buffers
  __shared__ __align__(16) short Bf[3][64 * LDP];  // [n][k] bf16, 3 buffers
  __shared__ float AssqL[64];
  __shared__ float BssqL[4][64];

  f32x4 acc00 = {0.f,0.f,0.f,0.f};
  f32x4 acc01 = acc00, acc10 = acc00, acc11 = acc00;

  // A staging: thread -> (row ar, 8 contiguous k at ac); two dwordx4 per chunk
  const int ar = t >> 2;
  const int ac = (t & 3) * 8;
  const float* aptr = h + ((size_t)(mt * 64 + ar) * Gn + g) * Dn + ac;

  // B staging: thread -> (col pair c2..c2+1, 4 d-rows at bq*4); dwordx2 loads,
  // each instruction = two 256B coalesced segments per wave.
  const int c2 = (t & 31) * 2;               // 0,2,..,62
  const int bq = t >> 5;                     // 0..7
  const float* bptr = W + (size_t)g * (Dn * Kn) + (size_t)(bq * 4) * Kn + nt * 64 + c2;

  const int koff = quad * 8;                 // A/B fragment: k = quad*8 + j
  const int m0   = wm * 32 + l15;
  const int n0   = wn * 32 + l15;

  float assq = 0.f, bs0 = 0.f, bs1 = 0.f;
  ASet A0, A1, A2;                           // named depth-3 sets: all accesses
  BSet B0, B1, B2;                           // compile-time static (rule #20)

  auto load_into = [&](int c, ASet& A, BSet& Bs) {   // issue chunk-c loads
    const int d0 = c * 32;
    A.a0 = *(const float4*)(aptr + d0);
    A.a1 = *(const float4*)(aptr + d0 + 4);
    const float* bp = bptr + (size_t)d0 * Kn;
    Bs.b0 = *(const float2*)(bp);
    Bs.b1 = *(const float2*)(bp + Kn);
    Bs.b2 = *(const float2*)(bp + 2 * Kn);
    Bs.b3 = *(const float2*)(bp + 3 * Kn);
  };

  auto pack_into = [&](int buf, const ASet& A, const BSet& Bs) {
    const float4 a0 = A.a0, a1 = A.a1;
    assq += a0.x*a0.x + a0.y*a0.y + a0.z*a0.z + a0.w*a0.w
          + a1.x*a1.x + a1.y*a1.y + a1.z*a1.z + a1.w*a1.w;
    uint4 ap;
    ap.x = pack2(a0.x, a0.y); ap.y = pack2(a0.z, a0.w);
    ap.z = pack2(a1.x, a1.y); ap.w = pack2(a1.z, a1.w);
    *(uint4*)&Af[buf][ar * LDP + ac] = ap;

    const float2 b0 = Bs.b0, b1 = Bs.b1, b2 = Bs.b2, b3 = Bs.b3;
    bs0 += b0.x*b0.x + b1.x*b1.x + b2.x*b2.x + b3.x*b3.x;
    bs1 += b0.y*b0.y + b1.y*b1.y + b2.y*b2.y + b3.y*b3.y;
    // col c2: k-run bq*4..bq*4+3 ; col c2+1: same k-run, next row
    uint2 w0, w1;
    w0.x = pack2(b0.x, b1.x); w0.y = pack2(b2.x, b3.x);
    w1.x = pack2(b0.y, b1.y); w1.y = pack2(b2.y, b3.y);
    *(uint2*)&Bf[buf][c2 * LDP + bq * 4]       = w0;
    *(uint2*)&Bf[buf][(c2 + 1) * LDP + bq * 4] = w1;
  };

  auto mfma_step = [&](int buf) {
    short8 af0 = *(const short8*)&Af[buf][m0 * LDP + koff];
    short8 af1 = *(const short8*)&Af[buf][(m0 + 16) * LDP + koff];
    short8 bf0 = *(const short8*)&Bf[buf][n0 * LDP + koff];
    short8 bf1 = *(const short8*)&Bf[buf][(n0 + 16) * LDP + koff];
    acc00 = __builtin_amdgcn_mfma_f32_16x16x32_bf16(af0, bf0, acc00, 0, 0, 0);
    acc01 = __builtin_amdgcn_mfma_f32_16x16x32_bf16(af0, bf1, acc01, 0, 0, 0);
    acc10 = __builtin_amdgcn_mfma_f32_16x16x32_bf16(af1, bf0, acc10, 0, 0, 0);
    acc11 = __builtin_amdgcn_mfma_f32_16x16x32_bf16(af1, bf1, acc11, 0, 0, 0);
  };

  // ---- prologue: chunks 0,1,2 in flight; pack 0 ----
  load_into(0, A0, B0);
  load_into(1, A1, B1);
  load_into(2, A2, B2);
  pack_into(0, A0, B0);

  // ---- main loop: 24 K-steps as 8 x 3-phase groups, ONE barrier per step ----
  // Phase p of group c handles iter c+p: loads chunk c+p+3 into set (c+p)%3,
  // packs chunk c+p+1 from set (c+p+1)%3 into buf (c+p+1)%3, mfma reads
  // buf (c+p)%3. With c stepping by 3, every set/buf index is a literal.
  // Reuse check: buf b's iter-c readers finish before bar(c+1); its next
  // writer (pack of chunk c+3) runs strictly after bar(c+2). Disjoint.
  for (int c = 0; c < 24; c += 3) {
    // phase 0: iter c
    if (c + 3 < 24) load_into(c + 3, A0, B0);
    pack_into(1, A1, B1);                    // chunk c+1 (always < 24)
    barrier_nodrain();
    mfma_step(0);

    // phase 1: iter c+1
    if (c + 4 < 24) load_into(c + 4, A1, B1);
    pack_into(2, A2, B2);                    // chunk c+2 (always < 24)
    barrier_nodrain();
    mfma_step(1);

    // phase 2: iter c+2
    if (c + 5 < 24) load_into(c + 5, A2, B2);
    if (c + 3 < 24) pack_into(0, A0, B0);    // chunk c+3
    barrier_nodrain();
    mfma_step(2);
  }

  // ---- block-reduce the norms ----
  assq += __shfl_xor(assq, 1);               // 4 threads (t&3) share row ar
  assq += __shfl_xor(assq, 2);
  if ((t & 3) == 0) AssqL[ar] = assq;
  // per-col B ssq: threads sharing a col differ in lane bit 5 (in-wave) and wave
  bs0 += __shfl_xor(bs0, 32);
  bs1 += __shfl_xor(bs1, 32);
  if (lane < 32) {                           // cols lane*2, lane*2+1
    BssqL[wave][lane * 2]     = bs0;
    BssqL[wave][lane * 2 + 1] = bs1;
  }
  __syncthreads();                           // one draining barrier: loop is done

  // ---- epilogue: scale by 1/max(||h_row||,eps) * 1/max(||w_col||,eps) ----
  // C/D layout: col = lane&15, row = quad*4 + reg
  const float ws0 = BssqL[0][n0] + BssqL[1][n0] + BssqL[2][n0] + BssqL[3][n0];
  const float ws1 = BssqL[0][n0+16] + BssqL[1][n0+16] + BssqL[2][n0+16] + BssqL[3][n0+16];
  const float wi0 = 1.0f / fmaxf(sqrtf(ws0), 1e-12f);
  const float wi1 = 1.0f / fmaxf(sqrtf(ws1), 1e-12f);

#pragma unroll
  for (int mi = 0; mi < 2; ++mi) {
#pragma unroll
    for (int r = 0; r < 4; ++r) {
      const int lr = wm * 32 + mi * 16 + quad * 4 + r;   // local row in tile
      const float hs = 1.0f / fmaxf(sqrtf(AssqL[lr]), 1e-12f);
      const float v0 = (mi ? acc10[r] : acc00[r]) * hs * wi0;
      const float v1 = (mi ? acc11[r] : acc01[r]) * hs * wi1;
      const int row = mt * 64 + lr;
      const size_t ob = ((size_t)row * Gn + g) * Kn + nt * 64;
      out[ob + wn * 32 + l15]      = v0;
      out[ob + wn * 32 + l15 + 16] = v1;
    }
  }
}

extern "C" void kernel_launch(void* const* d_in, const int* in_sizes, int n_in,
                              void* d_out, int out_size, void* d_ws, size_t ws_size,
                              hipStream_t stream) {
  const float* h = (const float*)d_in[0];          // [B,G,D]
  const float* W = (const float*)d_in[1];          // [G,D,K]
  float* out = (float*)d_out;                      // [B,G,K]
  hipLaunchKernelGGL(groupfc_kernel, dim3(832), dim3(256), 0, stream, h, W, out);
}

// Round 4
// 166.721 us; speedup vs baseline: 1.2620x; 1.0428x over previous
//
#include <hip/hip_runtime.h>

// Problem constants: h[B,G,D], W[G,D,K], out[B,G,K]
#define Gn   100
#define Bn   256
#define Dn   768
#define Kn   128
#define LDP  40   // LDS leading dim in shorts (32+8): 16B-aligned rows, mild aliasing

typedef __attribute__((ext_vector_type(8))) short short8;
typedef __attribute__((ext_vector_type(4))) float f32x4;

// pack two fp32 -> two bf16 (round-to-nearest, ties away) in 3 VALU
__device__ inline unsigned pack2(float lo, float hi) {
  union { float f; unsigned u; } a, b; a.f = lo; b.f = hi;
  return __builtin_amdgcn_perm(b.u + 0x8000u, a.u + 0x8000u, 0x07060302u);
}

// Non-draining block barrier: execution sync + LDS-write visibility ONLY.
// All global loads here target registers (per-wave private), so skipping the
// vmcnt drain is safe; lgkmcnt(0) makes LDS stores visible.
__device__ inline void barrier_nodrain() {
  asm volatile("s_waitcnt lgkmcnt(0)\n\ts_barrier" ::: "memory");
}

// R4: 128x128 tile, 512 threads (8 waves, 2x4 grid, 64x32 per wave).
// Rationale: R0/R3 converged at ~60us across different schedules; the
// invariant was 314 MB of global vector-load traffic (A x2, B x4 re-reads)
// at an observed ~5 TB/s L1-fill ceiling (50KB/CU/step = 8.1 B/cyc = the
// measured 6250 cyc/step). 128x128 tiles halve traffic to 157 MB
// (A x1, B x2). Grid 200 real blocks = 2 m-tiles x 100 groups; a group's
// two blocks share one XCD's L2 for W reuse. Depth-3 named-set register
// prefetch + 3-phase unroll + nodrain barriers carried over from R3.
struct ASet { float4 a0, a1; };
struct BSet { float2 b0, b1, b2, b3; };

__global__ __launch_bounds__(512, 2) void groupfc_kernel(
    const float* __restrict__ h, const float* __restrict__ W,
    float* __restrict__ out) {
  // grid 208 = 8*26; decode: xcd=id%8 -> g%8, j=id>>3: mt=j&1, g=xcd+8*(j>>1)
  // Both mt-blocks of a group have the same id%8 -> same XCD (round-robin).
  const int id  = blockIdx.x;
  const int xcd = id & 7;
  const int j   = id >> 3;                   // 0..25
  const int mt  = j & 1;                     // 0..1 (rows of 128)
  const int g   = xcd + (j >> 1) * 8;        // 0..103
  if (g >= Gn) return;                       // pad blocks exit before any barrier

  const int t    = threadIdx.x;
  const int lane = t & 63;
  const int wave = t >> 6;                   // 0..7
  const int wm   = wave >> 2;                // 0..1 (64-row halves)
  const int wn   = wave & 3;                 // 0..3 (32-col quarters)
  const int l15  = lane & 15, quad = lane >> 4;

  __shared__ __align__(16) short Af[3][128 * LDP];  // [m][k] bf16, 3 buffers
  __shared__ __align__(16) short Bf[3][128 * LDP];  // [n][k] bf16, 3 buffers
  __shared__ float AssqL[128];
  __shared__ float BssqL[8][128];

  f32x4 acc[4][2];
#pragma unroll
  for (int mi = 0; mi < 4; ++mi)
#pragma unroll
    for (int ni = 0; ni < 2; ++ni) acc[mi][ni] = (f32x4){0.f, 0.f, 0.f, 0.f};

  // A staging: thread -> (row ar 0..127, 8 contiguous k at ac); 2 dwordx4/chunk
  const int ar = t >> 2;
  const int ac = (t & 3) * 8;
  const float* aptr = h + ((size_t)(mt * 128 + ar) * Gn + g) * Dn + ac;

  // B staging: thread -> (col pair c2..c2+1, 4 d-rows at bq*4); 4 dwordx2/chunk
  const int c2 = (t & 63) * 2;               // 0,2,..,126
  const int bq = t >> 6;                     // 0..7 (== wave)
  const float* bptr = W + (size_t)g * (Dn * Kn) + (size_t)(bq * 4) * Kn + c2;

  const int koff = quad * 8;                 // A/B fragment: k = quad*8 + j
  const int m0   = wm * 64 + l15;            // frag rows m0 + mi*16
  const int n0   = wn * 32 + l15;            // frag cols n0 + ni*16

  float assq = 0.f, bs0 = 0.f, bs1 = 0.f;
  ASet A0, A1, A2;                           // named depth-3 sets: all accesses
  BSet B0, B1, B2;                           // compile-time static (rule #20)

  auto load_into = [&](int c, ASet& A, BSet& Bs) {   // issue chunk-c loads
    const int d0 = c * 32;
    A.a0 = *(const float4*)(aptr + d0);
    A.a1 = *(const float4*)(aptr + d0 + 4);
    const float* bp = bptr + (size_t)d0 * Kn;
    Bs.b0 = *(const float2*)(bp);
    Bs.b1 = *(const float2*)(bp + Kn);
    Bs.b2 = *(const float2*)(bp + 2 * Kn);
    Bs.b3 = *(const float2*)(bp + 3 * Kn);
  };

  auto pack_into = [&](int buf, const ASet& A, const BSet& Bs) {
    const float4 a0 = A.a0, a1 = A.a1;
    assq += a0.x*a0.x + a0.y*a0.y + a0.z*a0.z + a0.w*a0.w
          + a1.x*a1.x + a1.y*a1.y + a1.z*a1.z + a1.w*a1.w;
    uint4 ap;
    ap.x = pack2(a0.x, a0.y); ap.y = pack2(a0.z, a0.w);
    ap.z = pack2(a1.x, a1.y); ap.w = pack2(a1.z, a1.w);
    *(uint4*)&Af[buf][ar * LDP + ac] = ap;

    const float2 b0 = Bs.b0, b1 = Bs.b1, b2 = Bs.b2, b3 = Bs.b3;
    bs0 += b0.x*b0.x + b1.x*b1.x + b2.x*b2.x + b3.x*b3.x;
    bs1 += b0.y*b0.y + b1.y*b1.y + b2.y*b2.y + b3.y*b3.y;
    // col c2: k-run bq*4..bq*4+3 ; col c2+1: same k-run, next row
    uint2 w0, w1;
    w0.x = pack2(b0.x, b1.x); w0.y = pack2(b2.x, b3.x);
    w1.x = pack2(b0.y, b1.y); w1.y = pack2(b2.y, b3.y);
    *(uint2*)&Bf[buf][c2 * LDP + bq * 4]       = w0;
    *(uint2*)&Bf[buf][(c2 + 1) * LDP + bq * 4] = w1;
  };

  auto mfma_step = [&](int buf) {
    short8 af[4], bf[2];
#pragma unroll
    for (int mi = 0; mi < 4; ++mi)
      af[mi] = *(const short8*)&Af[buf][(m0 + mi * 16) * LDP + koff];
#pragma unroll
    for (int ni = 0; ni < 2; ++ni)
      bf[ni] = *(const short8*)&Bf[buf][(n0 + ni * 16) * LDP + koff];
#pragma unroll
    for (int mi = 0; mi < 4; ++mi)
#pragma unroll
      for (int ni = 0; ni < 2; ++ni)
        acc[mi][ni] = __builtin_amdgcn_mfma_f32_16x16x32_bf16(
            af[mi], bf[ni], acc[mi][ni], 0, 0, 0);
  };

  // ---- prologue: chunks 0,1,2 in flight; pack 0 ----
  load_into(0, A0, B0);
  load_into(1, A1, B1);
  load_into(2, A2, B2);
  pack_into(0, A0, B0);

  // ---- main loop: 24 K-steps as 8 x 3-phase groups, ONE barrier per step ----
  // Phase p handles iter c+p: load chunk c+p+3, pack chunk c+p+1 (consumed
  // 2 barriers after its load), mfma buf (c+p)%3. All set/buf indices literal.
  for (int c = 0; c < 24; c += 3) {
    // phase 0: iter c
    if (c + 3 < 24) load_into(c + 3, A0, B0);
    pack_into(1, A1, B1);                    // chunk c+1 (always < 24)
    barrier_nodrain();
    mfma_step(0);

    // phase 1: iter c+1
    if (c + 4 < 24) load_into(c + 4, A1, B1);
    pack_into(2, A2, B2);                    // chunk c+2 (always < 24)
    barrier_nodrain();
    mfma_step(1);

    // phase 2: iter c+2
    if (c + 5 < 24) load_into(c + 5, A2, B2);
    if (c + 3 < 24) pack_into(0, A0, B0);    // chunk c+3
    barrier_nodrain();
    mfma_step(2);
  }

  // ---- block-reduce the norms ----
  assq += __shfl_xor(assq, 1);               // 4 threads (t&3) share row ar
  assq += __shfl_xor(assq, 2);
  if ((t & 3) == 0) AssqL[ar] = assq;
  // B ssq: wave w holds partial ssq for cols c2/c2+1 (its 4 d-rows x 24 steps);
  // full col sum = sum over the 8 waves, done in the epilogue.
  BssqL[wave][c2]     = bs0;
  BssqL[wave][c2 + 1] = bs1;
  __syncthreads();                           // one draining barrier: loop is done

  // ---- epilogue: scale by 1/max(||h_row||,eps) * 1/max(||w_col||,eps) ----
  // C/D layout: col = lane&15, row = quad*4 + reg
  float wi[2];
#pragma unroll
  for (int ni = 0; ni < 2; ++ni) {
    const int col = n0 + ni * 16;
    float s = 0.f;
#pragma unroll
    for (int w = 0; w < 8; ++w) s += BssqL[w][col];
    wi[ni] = 1.0f / fmaxf(sqrtf(s), 1e-12f);
  }

#pragma unroll
  for (int mi = 0; mi < 4; ++mi) {
#pragma unroll
    for (int r = 0; r < 4; ++r) {
      const int lr = wm * 64 + mi * 16 + quad * 4 + r;   // local row in tile
      const float hs = 1.0f / fmaxf(sqrtf(AssqL[lr]), 1e-12f);
      const int row = mt * 128 + lr;
      const size_t ob = ((size_t)row * Gn + g) * Kn;
#pragma unroll
      for (int ni = 0; ni < 2; ++ni)
        out[ob + wn * 32 + ni * 16 + l15] = acc[mi][ni][r] * hs * wi[ni];
    }
  }
}

extern "C" void kernel_launch(void* const* d_in, const int* in_sizes, int n_in,
                              void* d_out, int out_size, void* d_ws, size_t ws_size,
                              hipStream_t stream) {
  const float* h = (const float*)d_in[0];          // [B,G,D]
  const float* W = (const float*)d_in[1];          // [G,D,K]
  float* out = (float*)d_out;                      // [B,G,K]
  hipLaunchKernelGGL(groupfc_kernel, dim3(208), dim3(512), 0, stream, h, W, out);
}

// Round 5
// 164.376 us; speedup vs baseline: 1.2800x; 1.0143x over previous
//
#include <hip/hip_runtime.h>

// Problem constants: h[B,G,D], W[G,D,K], out[B,G,K]
#define Gn   100
#define Bn   256
#define Dn   768
#define Kn   128
#define LDP  40   // LDS leading dim in shorts (32+8): 16B-aligned rows, mild aliasing

typedef __attribute__((ext_vector_type(8))) short short8;
typedef __attribute__((ext_vector_type(4))) float f32x4;

// pack two fp32 -> two bf16 (round-to-nearest, ties away) in 3 VALU
__device__ inline unsigned pack2(float lo, float hi) {
  union { float f; unsigned u; } a, b; a.f = lo; b.f = hi;
  return __builtin_amdgcn_perm(b.u + 0x8000u, a.u + 0x8000u, 0x07060302u);
}

// Non-draining block barrier: execution sync + LDS-write visibility ONLY.
// All global loads here target registers (per-wave private), so skipping the
// vmcnt drain is safe; lgkmcnt(0) makes LDS stores visible.
__device__ inline void barrier_nodrain() {
  asm volatile("s_waitcnt lgkmcnt(0)\n\ts_barrier" ::: "memory");
}

// R5: BK=64 (12 K-steps of two 32-sub-chunks), 2 LDS buffers, 128x128 tile.
// Rationale: R0/R3/R4 all sit at ~5.5-6.2k cyc/step with every pipe <16%
// busy; rate tracked in-flight bytes (R0 3.25 blk/CU @ 5 TB/s vs R4 1 blk/CU
// @ 2.9 TB/s) => latency-bound, throughput ~ MLP. This round doubles
// per-step in-flight loads (12 VMEM/thread/step) and halves barrier count.
// Addressing (LDP=40 sub-chunk layout, pack2, thread maps, epilogue) is
// carried unchanged from the passing R4 kernel.
struct A2Set { float4 a0, a1, a2, a3; };           // two 32-chunks of A
struct B2Set { float2 b0, b1, b2, b3, b4, b5, b6, b7; }; // two 32-chunks of B

__global__ __launch_bounds__(512, 2) void groupfc_kernel(
    const float* __restrict__ h, const float* __restrict__ W,
    float* __restrict__ out) {
  // grid 208 = 8*26; decode: xcd=id%8 -> g%8, j=id>>3: mt=j&1, g=xcd+8*(j>>1)
  // Both mt-blocks of a group have the same id%8 -> same XCD (round-robin).
  const int id  = blockIdx.x;
  const int xcd = id & 7;
  const int j   = id >> 3;                   // 0..25
  const int mt  = j & 1;                     // 0..1 (rows of 128)
  const int g   = xcd + (j >> 1) * 8;        // 0..103
  if (g >= Gn) return;                       // pad blocks exit before any barrier

  const int t    = threadIdx.x;
  const int lane = t & 63;
  const int wave = t >> 6;                   // 0..7
  const int wm   = wave >> 2;                // 0..1 (64-row halves)
  const int wn   = wave & 3;                 // 0..3 (32-col quarters)
  const int l15  = lane & 15, quad = lane >> 4;

  __shared__ __align__(16) short Af[2][2][128 * LDP];  // [buf][sub][m*k] bf16
  __shared__ __align__(16) short Bf[2][2][128 * LDP];  // [buf][sub][n*k] bf16
  __shared__ float AssqL[128];
  __shared__ float BssqL[8][128];

  f32x4 acc[4][2];
#pragma unroll
  for (int mi = 0; mi < 4; ++mi)
#pragma unroll
    for (int ni = 0; ni < 2; ++ni) acc[mi][ni] = (f32x4){0.f, 0.f, 0.f, 0.f};

  // A staging: thread -> (row ar 0..127, 8 contiguous k at ac); 2 dwordx4/chunk
  const int ar = t >> 2;
  const int ac = (t & 3) * 8;
  const float* aptr = h + ((size_t)(mt * 128 + ar) * Gn + g) * Dn + ac;

  // B staging: thread -> (col pair c2..c2+1, 4 d-rows at bq*4); 4 dwordx2/chunk
  const int c2 = (t & 63) * 2;               // 0,2,..,126
  const int bq = t >> 6;                     // 0..7 (== wave)
  const float* bptr = W + (size_t)g * (Dn * Kn) + (size_t)(bq * 4) * Kn + c2;

  const int koff = quad * 8;                 // A/B fragment: k = quad*8 + j
  const int m0   = wm * 64 + l15;            // frag rows m0 + mi*16
  const int n0   = wn * 32 + l15;            // frag cols n0 + ni*16

  float assq = 0.f, bs0 = 0.f, bs1 = 0.f;
  A2Set A0, A1;                              // two named double-sets: all
  B2Set B0, B1;                              // accesses literal (rule #20)

  auto load2_into = [&](int c0, A2Set& A, B2Set& Bs) {  // chunks c0, c0+1
    const int d0 = c0 * 32;
    A.a0 = *(const float4*)(aptr + d0);
    A.a1 = *(const float4*)(aptr + d0 + 4);
    A.a2 = *(const float4*)(aptr + d0 + 32);
    A.a3 = *(const float4*)(aptr + d0 + 36);
    const float* bp = bptr + (size_t)d0 * Kn;
    Bs.b0 = *(const float2*)(bp);
    Bs.b1 = *(const float2*)(bp + Kn);
    Bs.b2 = *(const float2*)(bp + 2 * Kn);
    Bs.b3 = *(const float2*)(bp + 3 * Kn);
    const float* bp2 = bp + 32 * Kn;
    Bs.b4 = *(const float2*)(bp2);
    Bs.b5 = *(const float2*)(bp2 + Kn);
    Bs.b6 = *(const float2*)(bp2 + 2 * Kn);
    Bs.b7 = *(const float2*)(bp2 + 3 * Kn);
  };

  auto pack_half = [&](int buf, int sub, const float4& x0, const float4& x1,
                       const float2& y0, const float2& y1,
                       const float2& y2, const float2& y3) {
    assq += x0.x*x0.x + x0.y*x0.y + x0.z*x0.z + x0.w*x0.w
          + x1.x*x1.x + x1.y*x1.y + x1.z*x1.z + x1.w*x1.w;
    uint4 ap;
    ap.x = pack2(x0.x, x0.y); ap.y = pack2(x0.z, x0.w);
    ap.z = pack2(x1.x, x1.y); ap.w = pack2(x1.z, x1.w);
    *(uint4*)&Af[buf][sub][ar * LDP + ac] = ap;

    bs0 += y0.x*y0.x + y1.x*y1.x + y2.x*y2.x + y3.x*y3.x;
    bs1 += y0.y*y0.y + y1.y*y1.y + y2.y*y2.y + y3.y*y3.y;
    uint2 w0, w1;
    w0.x = pack2(y0.x, y1.x); w0.y = pack2(y2.x, y3.x);
    w1.x = pack2(y0.y, y1.y); w1.y = pack2(y2.y, y3.y);
    *(uint2*)&Bf[buf][sub][c2 * LDP + bq * 4]       = w0;
    *(uint2*)&Bf[buf][sub][(c2 + 1) * LDP + bq * 4] = w1;
  };

  auto pack2_into = [&](int buf, const A2Set& A, const B2Set& Bs) {
    pack_half(buf, 0, A.a0, A.a1, Bs.b0, Bs.b1, Bs.b2, Bs.b3);
    pack_half(buf, 1, A.a2, A.a3, Bs.b4, Bs.b5, Bs.b6, Bs.b7);
  };

  auto mfma_step = [&](int buf) {            // consume both 32-sub-chunks
#pragma unroll
    for (int sub = 0; sub < 2; ++sub) {
      short8 af[4], bf[2];
#pragma unroll
      for (int mi = 0; mi < 4; ++mi)
        af[mi] = *(const short8*)&Af[buf][sub][(m0 + mi * 16) * LDP + koff];
#pragma unroll
      for (int ni = 0; ni < 2; ++ni)
        bf[ni] = *(const short8*)&Bf[buf][sub][(n0 + ni * 16) * LDP + koff];
#pragma unroll
      for (int mi = 0; mi < 4; ++mi)
#pragma unroll
        for (int ni = 0; ni < 2; ++ni)
          acc[mi][ni] = __builtin_amdgcn_mfma_f32_16x16x32_bf16(
              af[mi], bf[ni], acc[mi][ni], 0, 0, 0);
    }
  };

  // ---- prologue: set0 <- chunks 0,1; set1 <- chunks 2,3; pack set0 -> buf0
  load2_into(0, A0, B0);
  load2_into(2, A1, B1);
  pack2_into(0, A0, B0);

  // ---- main loop: 12 K-steps (BK=64), ONE non-draining barrier each ----
  // step s: load chunks 2s+4,2s+5 -> set s%2; barrier; mfma buf s%2;
  //         pack set (s+1)%2 (chunks 2s+2,2s+3) -> buf (s+1)%2.
  // Reuse: buf b written in [bar(s-1),bar(s)], read in [bar(s),bar(s+1)],
  // rewritten in [bar(s+1),bar(s+2)] -- every pair barrier-separated.
  for (int s = 0; s < 12; s += 2) {
    // even step s: set0/buf0
    if (2 * s + 4 < 24) load2_into(2 * s + 4, A0, B0);
    barrier_nodrain();
    mfma_step(0);
    pack2_into(1, A1, B1);                   // chunks 2s+2,2s+3 (always valid)

    // odd step s+1: set1/buf1
    if (2 * s + 6 < 24) load2_into(2 * s + 6, A1, B1);
    barrier_nodrain();
    mfma_step(1);
    if (2 * s + 4 < 24) pack2_into(0, A0, B0);   // chunks 2s+4,2s+5
  }

  // ---- block-reduce the norms ----
  assq += __shfl_xor(assq, 1);               // 4 threads (t&3) share row ar
  assq += __shfl_xor(assq, 2);
  if ((t & 3) == 0) AssqL[ar] = assq;
  // B ssq: wave w holds partial ssq for cols c2/c2+1 (its 4 d-rows x 24 chunks)
  BssqL[wave][c2]     = bs0;
  BssqL[wave][c2 + 1] = bs1;
  __syncthreads();                           // one draining barrier: loop is done

  // ---- epilogue: scale by 1/max(||h_row||,eps) * 1/max(||w_col||,eps) ----
  // C/D layout: col = lane&15, row = quad*4 + reg
  float wi[2];
#pragma unroll
  for (int ni = 0; ni < 2; ++ni) {
    const int col = n0 + ni * 16;
    float s = 0.f;
#pragma unroll
    for (int w = 0; w < 8; ++w) s += BssqL[w][col];
    wi[ni] = 1.0f / fmaxf(sqrtf(s), 1e-12f);
  }

#pragma unroll
  for (int mi = 0; mi < 4; ++mi) {
#pragma unroll
    for (int r = 0; r < 4; ++r) {
      const int lr = wm * 64 + mi * 16 + quad * 4 + r;   // local row in tile
      const float hs = 1.0f / fmaxf(sqrtf(AssqL[lr]), 1e-12f);
      const int row = mt * 128 + lr;
      const size_t ob = ((size_t)row * Gn + g) * Kn;
#pragma unroll
      for (int ni = 0; ni < 2; ++ni)
        out[ob + wn * 32 + ni * 16 + l15] = acc[mi][ni][r] * hs * wi[ni];
    }
  }
}

extern "C" void kernel_launch(void* const* d_in, const int* in_sizes, int n_in,
                              void* d_out, int out_size, void* d_ws, size_t ws_size,
                              hipStream_t stream) {
  const float* h = (const float*)d_in[0];          // [B,G,D]
  const float* W = (const float*)d_in[1];          // [G,D,K]
  float* out = (float*)d_out;                      // [B,G,K]
  hipLaunchKernelGGL(groupfc_kernel, dim3(208), dim3(512), 0, stream, h, W, out);
}